// Round 1
// baseline (398.032 us; speedup 1.0000x reference)
//
#include <hip/hip_runtime.h>

// Problem constants (from reference): B=32, L=4, W=512, D=768, fp32.
#define BB 32
#define LL 4
#define WW 512
#define DD 768
#define NCHUNK 16
#define WCHUNK (WW / NCHUNK)            // 32 words per chunk
#define D4 (DD / 4)                     // 192 float4 per (b,l,w) row
#define WORD_SIZE (BB * DD * WW)        // 12,582,912 floats

// ---------------------------------------------------------------------------
// Kernel 0: zero the whole output (word gaps must be 0; d_out is poisoned).
// ---------------------------------------------------------------------------
__global__ void zero_kernel(float4* __restrict__ out, int n4) {
    int i = blockIdx.x * blockDim.x + threadIdx.x;
    int stride = gridDim.x * blockDim.x;
    float4 z = make_float4(0.f, 0.f, 0.f, 0.f);
    for (; i < n4; i += stride) out[i] = z;
}

// ---------------------------------------------------------------------------
// Kernel 1: fused layer-sum + segment-sum + means.
// Grid: (NCHUNK, B). Block: 192 threads (3 waves); thread t owns d = 4t..4t+3.
// Sorted segment ids => runs are contiguous; interior runs of a chunk are
// exclusively owned (plain store); boundary runs use atomicAdd.
// ---------------------------------------------------------------------------
__global__ __launch_bounds__(192) void agg_kernel(
    const float* __restrict__ emb,   // [B, L, W, D]
    const int*   __restrict__ seg,   // [B, W] sorted per row
    float* __restrict__ word,        // [B, D, W]
    float* __restrict__ sent)        // [B, D]
{
    const int b   = blockIdx.y;
    const int w0  = blockIdx.x * WCHUNK;
    const int tid = threadIdx.x;           // 0..191
    const int d   = tid * 4;

    __shared__ int seg_sh[WCHUNK];
    if (tid < WCHUNK) seg_sh[tid] = seg[b * WW + w0 + tid];
    __syncthreads();

    const float4* e4 = (const float4*)emb;
    // float4 index of emb[b][l][w][d]: ((b*L + l)*W + w)*D4 + tid
    const size_t base   = (size_t)b * LL * WW * D4 + tid;
    const size_t lstride = (size_t)WW * D4;

    float* wrow = word + (size_t)b * DD * WW + (size_t)d * WW;  // + k*W for comp k, + s

    float4 sentacc = make_float4(0.f, 0.f, 0.f, 0.f);
    float4 acc = make_float4(0.f, 0.f, 0.f, 0.f);
    int  s_prev    = seg_sh[0];
    bool first_run = true;

#define FLUSH(S, ATOM) do {                                                  \
        float vx = acc.x * 0.25f, vy = acc.y * 0.25f,                        \
              vz = acc.z * 0.25f, vw = acc.w * 0.25f;                        \
        float* p = wrow + (S);                                               \
        if (ATOM) {                                                          \
            atomicAdd(p,          vx); atomicAdd(p +     WW, vy);            \
            atomicAdd(p + 2 * WW, vz); atomicAdd(p + 3 * WW, vw);            \
        } else {                                                             \
            p[0]      = vx; p[WW]     = vy;                                  \
            p[2 * WW] = vz; p[3 * WW] = vw;                                  \
        }                                                                    \
    } while (0)

    for (int wi = 0; wi < WCHUNK; ++wi) {
        const size_t off = base + (size_t)(w0 + wi) * D4;
        float4 t0 = e4[off];
        float4 t1 = e4[off + lstride];
        float4 t2 = e4[off + 2 * lstride];
        float4 t3 = e4[off + 3 * lstride];
        float4 t;
        t.x = (t0.x + t1.x) + (t2.x + t3.x);
        t.y = (t0.y + t1.y) + (t2.y + t3.y);
        t.z = (t0.z + t1.z) + (t2.z + t3.z);
        t.w = (t0.w + t1.w) + (t2.w + t3.w);

        sentacc.x += t.x; sentacc.y += t.y; sentacc.z += t.z; sentacc.w += t.w;

        const int s = seg_sh[wi];          // wave-uniform
        if (wi == 0) {
            acc = t; s_prev = s;
        } else if (s != s_prev) {
            FLUSH(s_prev, first_run);      // first run may extend left of chunk
            first_run = false;
            acc = t; s_prev = s;
        } else {
            acc.x += t.x; acc.y += t.y; acc.z += t.z; acc.w += t.w;
        }
    }
    FLUSH(s_prev, true);                   // last run may extend right of chunk
#undef FLUSH

    // sent mean over (W, L): one atomic per (chunk, d) — 512 adds per target.
    const float sscale = 1.0f / (float)(WW * LL);
    float* sp = sent + (size_t)b * DD + d;
    atomicAdd(sp + 0, sentacc.x * sscale);
    atomicAdd(sp + 1, sentacc.y * sscale);
    atomicAdd(sp + 2, sentacc.z * sscale);
    atomicAdd(sp + 3, sentacc.w * sscale);
}

extern "C" void kernel_launch(void* const* d_in, const int* in_sizes, int n_in,
                              void* d_out, int out_size, void* d_ws, size_t ws_size,
                              hipStream_t stream) {
    const float* emb = (const float*)d_in[0];   // [32,4,512,768] fp32
    const int*   seg = (const int*)d_in[1];     // [32,512] int32, sorted per row
    float* out  = (float*)d_out;
    float* word = out;                          // [B, D, W]
    float* sent = out + WORD_SIZE;              // [B, D]

    const int n4 = out_size / 4;                // out_size = 12,607,488 (div by 4)
    zero_kernel<<<dim3(512), dim3(256), 0, stream>>>((float4*)out, n4);
    agg_kernel<<<dim3(NCHUNK, BB), dim3(192), 0, stream>>>(emb, seg, word, sent);
}

// Round 2
// 310.092 us; speedup vs baseline: 1.2836x; 1.2836x over previous
//
#include <hip/hip_runtime.h>

// Problem: B=32, L=4, W=512, D=768, fp32.
// out = [word: B*D*W][sent: B*D], word[b][d][s] = (1/L)*sum_{w:seg=s} sum_l emb[b][l][w][d]
#define BB 32
#define LL 4
#define WW 512
#define DD 768
#define D4 (DD / 4)                     // 192 float4 per row
#define WORD_SIZE (BB * DD * WW)        // 12,582,912 floats
#define NCHUNK 64
#define WCHUNK (WW / NCHUNK)            // 8 words per chunk

// ---------------------------------------------------------------------------
// Phase A: layer-sum + segment-sum into ws[B][W][D] (natural layout ->
// coalesced 3KB-row flushes). Sorted ids => runs contiguous; atomics only for
// runs that actually cross a chunk boundary. Also accumulates sent via atomics.
// Grid: (NCHUNK, B), block 192 (thread t owns d=4t..4t+3).
// ---------------------------------------------------------------------------
__global__ __launch_bounds__(192) void phaseA(
    const float* __restrict__ emb,   // [B, L, W, D]
    const int*   __restrict__ seg,   // [B, W] sorted per row
    float* __restrict__ ws,          // [B, W, D] segment sums (layer-meaned)
    float* __restrict__ sent)        // [B, D] (pre-zeroed)
{
    const int b   = blockIdx.y;
    const int w0  = blockIdx.x * WCHUNK;
    const int tid = threadIdx.x;           // 0..191
    const int d   = tid * 4;

    __shared__ int seg_sh[WCHUNK];
    __shared__ int nb[2];
    if (tid < WCHUNK) seg_sh[tid] = seg[b * WW + w0 + tid];
    if (tid == 192 - 2) nb[0] = (w0 > 0)           ? seg[b * WW + w0 - 1]      : -1;
    if (tid == 192 - 1) nb[1] = (w0 + WCHUNK < WW) ? seg[b * WW + w0 + WCHUNK] : -1;
    __syncthreads();
    const bool atomL = (nb[0] == seg_sh[0]);           // first run extends left
    const bool atomR = (nb[1] == seg_sh[WCHUNK - 1]);  // last run extends right

    const float4* e4 = (const float4*)emb;
    const size_t base    = (size_t)b * LL * WW * D4 + tid;
    const size_t lstride = (size_t)WW * D4;

    float4 sentacc = make_float4(0.f, 0.f, 0.f, 0.f);
    float4 acc     = make_float4(0.f, 0.f, 0.f, 0.f);
    int  s_prev    = seg_sh[0];
    bool first_run = true;

#define FLUSH(S, ATOM) do {                                                  \
        float vx = acc.x * 0.25f, vy = acc.y * 0.25f,                        \
              vz = acc.z * 0.25f, vw = acc.w * 0.25f;                        \
        float* p = ws + ((size_t)b * WW + (S)) * DD + d;                     \
        if (ATOM) {                                                          \
            atomicAdd(p + 0, vx); atomicAdd(p + 1, vy);                      \
            atomicAdd(p + 2, vz); atomicAdd(p + 3, vw);                      \
        } else {                                                             \
            float4 v = make_float4(vx, vy, vz, vw);                          \
            *(float4*)p = v;                                                 \
        }                                                                    \
    } while (0)

#pragma unroll
    for (int wi = 0; wi < WCHUNK; ++wi) {
        const size_t off = base + (size_t)(w0 + wi) * D4;
        float4 t0 = e4[off];
        float4 t1 = e4[off + lstride];
        float4 t2 = e4[off + 2 * lstride];
        float4 t3 = e4[off + 3 * lstride];
        float4 t;
        t.x = (t0.x + t1.x) + (t2.x + t3.x);
        t.y = (t0.y + t1.y) + (t2.y + t3.y);
        t.z = (t0.z + t1.z) + (t2.z + t3.z);
        t.w = (t0.w + t1.w) + (t2.w + t3.w);

        sentacc.x += t.x; sentacc.y += t.y; sentacc.z += t.z; sentacc.w += t.w;

        const int s = seg_sh[wi];          // wave-uniform
        if (wi == 0) {
            acc = t; s_prev = s;
        } else if (s != s_prev) {
            FLUSH(s_prev, first_run && atomL);
            first_run = false;
            acc = t; s_prev = s;
        } else {
            acc.x += t.x; acc.y += t.y; acc.z += t.z; acc.w += t.w;
        }
    }
    FLUSH(s_prev, atomR || (first_run && atomL));
#undef FLUSH

    const float sscale = 1.0f / (float)(WW * LL);
    float* sp = sent + (size_t)b * DD + d;
    atomicAdd(sp + 0, sentacc.x * sscale);
    atomicAdd(sp + 1, sentacc.y * sscale);
    atomicAdd(sp + 2, sentacc.z * sscale);
    atomicAdd(sp + 3, sentacc.w * sscale);
}

// ---------------------------------------------------------------------------
// Phase B: transpose ws[B][W][D] -> word[B][D][W], zero-filling unused segment
// columns (flags from seg row; poisoned ws rows are never read).
// Grid: (W/64, D/64, B) = (8, 12, 32), block 256. LDS tile 64x65 (+1 pad).
// ---------------------------------------------------------------------------
__global__ __launch_bounds__(256) void phaseB(
    const float* __restrict__ ws,    // [B, W, D]
    const int*   __restrict__ seg,   // [B, W]
    float* __restrict__ word)        // [B, D, W]
{
    const int s0 = blockIdx.x * 64;
    const int d0 = blockIdx.y * 64;
    const int b  = blockIdx.z;
    const int tid = threadIdx.x;     // 0..255

    __shared__ float tile[64 * 65];
    __shared__ int used[64];

    if (tid < 64) used[tid] = 0;
    __syncthreads();
    // mark used segments in [s0, s0+64)
    {
        int s = seg[b * WW + tid];
        if (s >= s0 && s < s0 + 64) used[s - s0] = 1;
        s = seg[b * WW + tid + 256];
        if (s >= s0 && s < s0 + 64) used[s - s0] = 1;
    }
    __syncthreads();

    const float4* w4 = (const float4*)ws;
    const int col4 = tid & 15;       // float4 column within d-tile
    const int rbase = tid >> 4;      // 0..15

#pragma unroll
    for (int k = 0; k < 4; ++k) {
        const int row = k * 16 + rbase;          // s row within tile
        float4 v = make_float4(0.f, 0.f, 0.f, 0.f);
        if (used[row])
            v = w4[((size_t)b * WW + s0 + row) * D4 + (d0 >> 2) + col4];
        float* tp = &tile[row * 65 + col4 * 4];
        tp[0] = v.x; tp[1] = v.y; tp[2] = v.z; tp[3] = v.w;   // 2-way bank alias: free
    }
    __syncthreads();

#pragma unroll
    for (int k = 0; k < 4; ++k) {
        const int dr = k * 16 + rbase;           // d row within tile
        const int s4 = col4;                     // float4 along s
        float4 o;
        o.x = tile[(4 * s4 + 0) * 65 + dr];
        o.y = tile[(4 * s4 + 1) * 65 + dr];
        o.z = tile[(4 * s4 + 2) * 65 + dr];
        o.w = tile[(4 * s4 + 3) * 65 + dr];
        float4* wp = (float4*)(word + ((size_t)b * DD + d0 + dr) * WW + s0);
        wp[s4] = o;
    }
}

extern "C" void kernel_launch(void* const* d_in, const int* in_sizes, int n_in,
                              void* d_out, int out_size, void* d_ws, size_t ws_size,
                              hipStream_t stream) {
    const float* emb = (const float*)d_in[0];   // [32,4,512,768] fp32
    const int*   seg = (const int*)d_in[1];     // [32,512] int32, sorted per row
    float* out  = (float*)d_out;
    float* word = out;                          // [B, D, W]
    float* sent = out + WORD_SIZE;              // [B, D]
    float* ws   = (float*)d_ws;                 // [B, W, D] = 50.3 MB

    hipMemsetAsync(sent, 0, (size_t)BB * DD * sizeof(float), stream);
    phaseA<<<dim3(NCHUNK, BB), dim3(192), 0, stream>>>(emb, seg, ws, sent);
    phaseB<<<dim3(WW / 64, DD / 64, BB), dim3(256), 0, stream>>>(ws, seg, word);
}